// Round 17
// baseline (89.312 us; speedup 1.0000x reference)
//
#include <hip/hip_runtime.h>
#include <hip/hip_bf16.h>

#define N_NODES 100000
#define D 64
#define BSHIFT 8
#define BNODES 256        // nodes per bucket
#define NB 391            // ceil(100000/256)
#define CHUNK 8192
#define LDS_CAP 4096      // edges per bucket in LDS (mean 3200, sd ~56)

typedef __attribute__((ext_vector_type(8))) _Float16 half8;

// ---------- K1: role-split — hist blocks (int4 reads) / conv-only blocks ----------
__global__ void convhist(const float4* __restrict__ feat4, float4* __restrict__ feat16,
                         int n4pairs, const int* __restrict__ dst, int* __restrict__ counts,
                         int nchunk, int n_edges) {
    int c = blockIdx.x;
    if (c >= nchunk) {
        int nb = gridDim.x - nchunk;
        int bi = c - nchunk;
        for (int i = bi * blockDim.x + threadIdx.x; i < n4pairs; i += nb * blockDim.x) {
            float4 a = feat4[i * 2];
            float4 b = feat4[i * 2 + 1];
            half8 h;
            h[0] = (_Float16)a.x; h[1] = (_Float16)a.y;
            h[2] = (_Float16)a.z; h[3] = (_Float16)a.w;
            h[4] = (_Float16)b.x; h[5] = (_Float16)b.y;
            h[6] = (_Float16)b.z; h[7] = (_Float16)b.w;
            *reinterpret_cast<half8*>(&feat16[i]) = h;
        }
        return;
    }
    __shared__ int h[NB];
    int tid = threadIdx.x;
    for (int i = tid; i < NB; i += blockDim.x) h[i] = 0;
    __syncthreads();
    int s = c * CHUNK, e = min(s + CHUNK, n_edges);
    int m = e - s;
    const int4* d4 = reinterpret_cast<const int4*>(dst + s);   // s is 8192-aligned
    int nv = m >> 2;
    for (int k = tid; k < nv; k += blockDim.x) {
        int4 dv = d4[k];
        atomicAdd(&h[dv.x >> BSHIFT], 1);
        atomicAdd(&h[dv.y >> BSHIFT], 1);
        atomicAdd(&h[dv.z >> BSHIFT], 1);
        atomicAdd(&h[dv.w >> BSHIFT], 1);
    }
    for (int i = s + (nv << 2) + tid; i < e; i += blockDim.x)
        atomicAdd(&h[dst[i] >> BSHIFT], 1);
    __syncthreads();
    for (int b = tid; b < NB; b += blockDim.x)
        counts[(size_t)b * nchunk + c] = h[b];   // bucket-major
}

// ---------- K2: per-bucket scan over chunk counts; LAST block also scans totals->base ----------
__global__ void scanBase(int* __restrict__ counts, int* __restrict__ totals,
                         int* __restrict__ base, int* __restrict__ done,
                         int nchunk, int n_edges) {
    __shared__ int s[256];
    __shared__ int amLast;
    int b = blockIdx.x;
    int tid = threadIdx.x;      // 256
    int carry = 0;
    int* row = counts + (size_t)b * nchunk;
    for (int t0 = 0; t0 < nchunk; t0 += 256) {
        int i = t0 + tid;
        int v = (i < nchunk) ? row[i] : 0;
        s[tid] = v;
        __syncthreads();
        for (int off = 1; off < 256; off <<= 1) {
            int t = (tid >= off) ? s[tid - off] : 0;
            __syncthreads();
            s[tid] += t;
            __syncthreads();
        }
        if (i < nchunk) row[i] = s[tid] - v + carry;
        carry += s[255];
        __syncthreads();
    }
    if (tid == 0) totals[b] = carry;

    // last block scans the totals into base
    __threadfence();
    if (tid == 0) amLast = (atomicAdd(done, 1) == gridDim.x - 1);
    __syncthreads();
    if (!amLast) return;

    volatile int* vtot = (volatile int*)totals;
    int carry2 = 0;
    for (int t0 = 0; t0 < NB; t0 += 256) {
        int i = t0 + tid;
        int v = (i < NB) ? vtot[i] : 0;
        s[tid] = v;
        __syncthreads();
        for (int off = 1; off < 256; off <<= 1) {
            int t = (tid >= off) ? s[tid - off] : 0;
            __syncthreads();
            s[tid] += t;
            __syncthreads();
        }
        if (i < NB) base[i] = s[tid] - v + carry2;
        carry2 += s[255];
        __syncthreads();
    }
    if (tid == 0) base[NB] = n_edges;
}

// ---------- K3: scatter to bucket order, int4 reads + LDS-staged coalesced writes ----------
__global__ void scatter2(const int* __restrict__ src, const int* __restrict__ dst,
                         const int* __restrict__ counts, const int* __restrict__ base,
                         unsigned* __restrict__ sorted, int nchunk, int n_edges) {
    __shared__ int lcnt[NB];
    __shared__ int gb[NB];
    __shared__ int lcur[NB];
    __shared__ int scn[512];
    __shared__ unsigned sval[CHUNK];     // staged packed edges (32 KB)
    __shared__ unsigned sgad[CHUNK];     // staged global addresses (32 KB)
    int tid = threadIdx.x;               // 1024
    int c = blockIdx.x;
    int s = c * CHUNK, e = min(s + CHUNK, n_edges);

    for (int b = tid; b < NB; b += 1024) lcnt[b] = 0;
    __syncthreads();

    unsigned pv[8];
    short pb[8];
    #pragma unroll
    for (int p = 0; p < 2; p++) {
        int i0 = s + p * 4096 + tid * 4;
        if (i0 + 3 < e) {
            int4 dv = *reinterpret_cast<const int4*>(dst + i0);
            int4 sv = *reinterpret_cast<const int4*>(src + i0);
            int b0 = dv.x >> BSHIFT, b1 = dv.y >> BSHIFT,
                b2 = dv.z >> BSHIFT, b3 = dv.w >> BSHIFT;
            pv[p * 4 + 0] = ((unsigned)(dv.x & (BNODES - 1)) << 17) | (unsigned)sv.x;
            pv[p * 4 + 1] = ((unsigned)(dv.y & (BNODES - 1)) << 17) | (unsigned)sv.y;
            pv[p * 4 + 2] = ((unsigned)(dv.z & (BNODES - 1)) << 17) | (unsigned)sv.z;
            pv[p * 4 + 3] = ((unsigned)(dv.w & (BNODES - 1)) << 17) | (unsigned)sv.w;
            pb[p * 4 + 0] = (short)b0; pb[p * 4 + 1] = (short)b1;
            pb[p * 4 + 2] = (short)b2; pb[p * 4 + 3] = (short)b3;
            atomicAdd(&lcnt[b0], 1); atomicAdd(&lcnt[b1], 1);
            atomicAdd(&lcnt[b2], 1); atomicAdd(&lcnt[b3], 1);
        } else {
            #pragma unroll
            for (int j = 0; j < 4; j++) {
                int i = i0 + j;
                if (i < e) {
                    int d = dst[i];
                    int b = d >> BSHIFT;
                    pv[p * 4 + j] = ((unsigned)(d & (BNODES - 1)) << 17) | (unsigned)src[i];
                    pb[p * 4 + j] = (short)b;
                    atomicAdd(&lcnt[b], 1);
                } else pb[p * 4 + j] = -1;
            }
        }
    }
    __syncthreads();

    if (tid < 512) scn[tid] = (tid < NB) ? lcnt[tid] : 0;
    __syncthreads();
    for (int off = 1; off < 512; off <<= 1) {
        int t = 0;
        if (tid < 512 && tid >= off) t = scn[tid - off];
        __syncthreads();
        if (tid < 512) scn[tid] += t;
        __syncthreads();
    }
    if (tid < NB) {
        int excl = scn[tid] - lcnt[tid];
        lcur[tid] = excl;
        gb[tid] = base[tid] + counts[(size_t)tid * nchunk + c] - excl;
    }
    __syncthreads();

    #pragma unroll
    for (int k = 0; k < 8; k++) {
        if (pb[k] >= 0) {
            int b = pb[k];
            int q = atomicAdd(&lcur[b], 1);
            sval[q] = pv[k];
            sgad[q] = (unsigned)(gb[b] + q);
        }
    }
    __syncthreads();

    int m = e - s;
    for (int i = tid; i < m; i += 1024)
        sorted[sgad[i]] = sval[i];
}

// ---------- K4: per-bucket counting sort into LDS + fp16 gather ----------
__global__ void sortGather(const _Float16* __restrict__ feat16,
                           const unsigned* __restrict__ sorted,
                           const int* __restrict__ base,
                           unsigned* __restrict__ sorted2,   // spill path only
                           float* __restrict__ out) {
    __shared__ int cnt[BNODES];
    __shared__ int scn[BNODES];
    __shared__ int noff[BNODES + 1];
    __shared__ int cur[BNODES];
    __shared__ unsigned lsrc[LDS_CAP];
    int tid = threadIdx.x;      // 1024
    int b = blockIdx.x;

    int start = base[b];
    int cntb = base[b + 1] - start;
    bool big = (cntb > LDS_CAP);

    unsigned p0 = 0, p1 = 0, p2 = 0, p3 = 0;
    int i0 = tid, i1 = tid + 1024, i2 = tid + 2048, i3 = tid + 3072;
    if (!big) {
        if (i0 < cntb) p0 = sorted[start + i0];
        if (i1 < cntb) p1 = sorted[start + i1];
        if (i2 < cntb) p2 = sorted[start + i2];
        if (i3 < cntb) p3 = sorted[start + i3];
    }

    if (tid < BNODES) cnt[tid] = 0;
    __syncthreads();
    if (!big) {
        if (i0 < cntb) atomicAdd(&cnt[(p0 >> 17) & (BNODES - 1)], 1);
        if (i1 < cntb) atomicAdd(&cnt[(p1 >> 17) & (BNODES - 1)], 1);
        if (i2 < cntb) atomicAdd(&cnt[(p2 >> 17) & (BNODES - 1)], 1);
        if (i3 < cntb) atomicAdd(&cnt[(p3 >> 17) & (BNODES - 1)], 1);
    } else {
        for (int i = tid; i < cntb; i += 1024)
            atomicAdd(&cnt[(sorted[start + i] >> 17) & (BNODES - 1)], 1);
    }
    __syncthreads();

    int v = (tid < BNODES) ? cnt[tid] : 0;
    if (tid < BNODES) scn[tid] = v;
    __syncthreads();
    for (int off = 1; off < BNODES; off <<= 1) {
        int t = 0;
        if (tid < BNODES && tid >= off) t = scn[tid - off];
        __syncthreads();
        if (tid < BNODES) scn[tid] += t;
        __syncthreads();
    }
    if (tid < BNODES) { noff[tid] = scn[tid] - v; cur[tid] = scn[tid] - v; }
    if (tid == 0) noff[BNODES] = cntb;
    __syncthreads();

    if (!big) {
        if (i0 < cntb) { int q = atomicAdd(&cur[(p0 >> 17) & (BNODES - 1)], 1); lsrc[q] = p0 & 0x1FFFF; }
        if (i1 < cntb) { int q = atomicAdd(&cur[(p1 >> 17) & (BNODES - 1)], 1); lsrc[q] = p1 & 0x1FFFF; }
        if (i2 < cntb) { int q = atomicAdd(&cur[(p2 >> 17) & (BNODES - 1)], 1); lsrc[q] = p2 & 0x1FFFF; }
        if (i3 < cntb) { int q = atomicAdd(&cur[(p3 >> 17) & (BNODES - 1)], 1); lsrc[q] = p3 & 0x1FFFF; }
    } else {
        for (int i = tid; i < cntb; i += 1024) {
            unsigned p = sorted[start + i];
            int q = atomicAdd(&cur[(p >> 17) & (BNODES - 1)], 1);
            sorted2[start + q] = p & 0x1FFFF;
        }
    }
    __syncthreads();

    int g = tid >> 3, gl = tid & 7;
    for (int n = g; n < BNODES; n += 128) {
        int node = (b << BSHIFT) + n;
        if (node >= N_NODES) break;
        int off = noff[n], endn = noff[n + 1];
        int deg = endn - off;
        float4 accA = make_float4(0.f, 0.f, 0.f, 0.f);
        float4 accB = make_float4(0.f, 0.f, 0.f, 0.f);
        int e = off;
        if (!big) {
            for (; e + 4 <= endn; e += 4) {
                int s0 = lsrc[e], s1 = lsrc[e + 1], s2 = lsrc[e + 2], s3 = lsrc[e + 3];
                half8 v0 = *reinterpret_cast<const half8*>(&feat16[(size_t)s0 * D + gl * 8]);
                half8 v1 = *reinterpret_cast<const half8*>(&feat16[(size_t)s1 * D + gl * 8]);
                half8 v2 = *reinterpret_cast<const half8*>(&feat16[(size_t)s2 * D + gl * 8]);
                half8 v3 = *reinterpret_cast<const half8*>(&feat16[(size_t)s3 * D + gl * 8]);
                accA.x += (float)v0[0] + (float)v1[0] + (float)v2[0] + (float)v3[0];
                accA.y += (float)v0[1] + (float)v1[1] + (float)v2[1] + (float)v3[1];
                accA.z += (float)v0[2] + (float)v1[2] + (float)v2[2] + (float)v3[2];
                accA.w += (float)v0[3] + (float)v1[3] + (float)v2[3] + (float)v3[3];
                accB.x += (float)v0[4] + (float)v1[4] + (float)v2[4] + (float)v3[4];
                accB.y += (float)v0[5] + (float)v1[5] + (float)v2[5] + (float)v3[5];
                accB.z += (float)v0[6] + (float)v1[6] + (float)v2[6] + (float)v3[6];
                accB.w += (float)v0[7] + (float)v1[7] + (float)v2[7] + (float)v3[7];
            }
            for (; e < endn; e++) {
                int s = lsrc[e];
                half8 vv = *reinterpret_cast<const half8*>(&feat16[(size_t)s * D + gl * 8]);
                accA.x += (float)vv[0]; accA.y += (float)vv[1];
                accA.z += (float)vv[2]; accA.w += (float)vv[3];
                accB.x += (float)vv[4]; accB.y += (float)vv[5];
                accB.z += (float)vv[6]; accB.w += (float)vv[7];
            }
        } else {
            for (; e < endn; e++) {
                int s = (int)sorted2[start + e];
                half8 vv = *reinterpret_cast<const half8*>(&feat16[(size_t)s * D + gl * 8]);
                accA.x += (float)vv[0]; accA.y += (float)vv[1];
                accA.z += (float)vv[2]; accA.w += (float)vv[3];
                accB.x += (float)vv[4]; accB.y += (float)vv[5];
                accB.z += (float)vv[6]; accB.w += (float)vv[7];
            }
        }
        float inv = (deg > 0) ? 1.0f / (float)deg : 0.0f;
        float4 oA = make_float4(accA.x * inv, accA.y * inv, accA.z * inv, accA.w * inv);
        float4 oB = make_float4(accB.x * inv, accB.y * inv, accB.z * inv, accB.w * inv);
        float* orow = &out[(size_t)node * D + gl * 8];
        *reinterpret_cast<float4*>(orow) = oA;
        *reinterpret_cast<float4*>(orow + 4) = oB;
    }
}

// ---------- fallback (atomic scatter) if ws too small ----------
__global__ void gcn_scatter(const float* __restrict__ feat, const int* __restrict__ src,
                            const int* __restrict__ dst, float* __restrict__ out,
                            float* __restrict__ deg, int n_edges) {
    long long gtid = (long long)blockIdx.x * blockDim.x + threadIdx.x;
    int edge = (int)(gtid >> 6);
    int lane = threadIdx.x & 63;
    if (edge >= n_edges) return;
    atomicAdd(&out[(long long)dst[edge] * D + lane],
              feat[(long long)src[edge] * D + lane]);
    if (lane == 0) atomicAdd(&deg[dst[edge]], 1.0f);
}
__global__ void gcn_finalize(float* __restrict__ out, const float* __restrict__ deg,
                             int total) {
    int i = blockIdx.x * blockDim.x + threadIdx.x;
    if (i >= total) return;
    float dg = deg[i >> 6];
    out[i] = (dg > 0.0f) ? out[i] / dg : 0.0f;
}

extern "C" void kernel_launch(void* const* d_in, const int* in_sizes, int n_in,
                              void* d_out, int out_size, void* d_ws, size_t ws_size,
                              hipStream_t stream) {
    const float* feat = (const float*)d_in[0];
    const int* src = (const int*)d_in[1];
    const int* dst = (const int*)d_in[2];
    float* out = (float*)d_out;
    int n_edges = in_sizes[1];

    int nchunk = (n_edges + CHUNK - 1) / CHUNK;
    size_t ncounts = (size_t)NB * nchunk;
    size_t f16_bytes = (size_t)N_NODES * D * sizeof(_Float16);   // 12.8 MB
    size_t need = f16_bytes + (ncounts + NB + NB + 1 + 1) * sizeof(int)
                + (size_t)n_edges * 2 * sizeof(unsigned);

    if (ws_size < need) {
        float* deg = (float*)d_ws;
        int total = N_NODES * D;
        hipMemsetAsync(out, 0, (size_t)total * sizeof(float), stream);
        hipMemsetAsync(deg, 0, (size_t)N_NODES * sizeof(float), stream);
        long long threads = (long long)n_edges * 64;
        int grid = (int)((threads + 255) / 256);
        gcn_scatter<<<grid, 256, 0, stream>>>(feat, src, dst, out, deg, n_edges);
        gcn_finalize<<<(total + 255) / 256, 256, 0, stream>>>(out, deg, total);
        return;
    }

    char* wp = (char*)d_ws;
    _Float16* feat16 = (_Float16*)wp;            wp += f16_bytes;
    int* counts = (int*)wp;                      wp += ncounts * sizeof(int);
    int* totals = (int*)wp;                      wp += (size_t)NB * sizeof(int);
    int* base = (int*)wp;                        wp += (size_t)(NB + 1) * sizeof(int);
    int* done = (int*)wp;                        wp += sizeof(int);
    unsigned* sorted = (unsigned*)wp;            wp += (size_t)n_edges * sizeof(unsigned);
    unsigned* sorted2 = (unsigned*)wp;           // spill path only

    hipMemsetAsync(done, 0, sizeof(int), stream);

    int n4pairs = N_NODES * D / 8;
    int chgrid = nchunk + 256;                   // hist blocks + 256 dedicated conv blocks
    convhist<<<chgrid, 1024, 0, stream>>>((const float4*)feat, (float4*)feat16,
                                          n4pairs, dst, counts, nchunk, n_edges);
    scanBase<<<NB, 256, 0, stream>>>(counts, totals, base, done, nchunk, n_edges);
    scatter2<<<nchunk, 1024, 0, stream>>>(src, dst, counts, base, sorted,
                                          nchunk, n_edges);
    sortGather<<<NB, 1024, 0, stream>>>(feat16, sorted, base, sorted2, out);
}

// Round 18
// 84.362 us; speedup vs baseline: 1.0587x; 1.0587x over previous
//
#include <hip/hip_runtime.h>
#include <hip/hip_bf16.h>

#define N_NODES 100000
#define D 64
#define BSHIFT 8
#define BNODES 256        // nodes per bucket
#define NB 391            // ceil(100000/256)
#define CHUNK 8192
#define LDS_CAP 4096      // edges per bucket in LDS (mean 3200, sd ~56)

typedef __attribute__((ext_vector_type(8))) _Float16 half8;

// ---------- K1: role-split — hist blocks (int4 reads) / conv-only blocks ----------
// Also zeroes the `done` counter consumed by scanBase (stream-ordered after us).
__global__ void convhist(const float4* __restrict__ feat4, float4* __restrict__ feat16,
                         int n4pairs, const int* __restrict__ dst, int* __restrict__ counts,
                         int* __restrict__ done, int nchunk, int n_edges) {
    int c = blockIdx.x;
    if (c == 0 && threadIdx.x == 0) *done = 0;
    if (c >= nchunk) {
        int nb = gridDim.x - nchunk;
        int bi = c - nchunk;
        for (int i = bi * blockDim.x + threadIdx.x; i < n4pairs; i += nb * blockDim.x) {
            float4 a = feat4[i * 2];
            float4 b = feat4[i * 2 + 1];
            half8 h;
            h[0] = (_Float16)a.x; h[1] = (_Float16)a.y;
            h[2] = (_Float16)a.z; h[3] = (_Float16)a.w;
            h[4] = (_Float16)b.x; h[5] = (_Float16)b.y;
            h[6] = (_Float16)b.z; h[7] = (_Float16)b.w;
            *reinterpret_cast<half8*>(&feat16[i]) = h;
        }
        return;
    }
    __shared__ int h[NB];
    int tid = threadIdx.x;
    for (int i = tid; i < NB; i += blockDim.x) h[i] = 0;
    __syncthreads();
    int s = c * CHUNK, e = min(s + CHUNK, n_edges);
    int m = e - s;
    const int4* d4 = reinterpret_cast<const int4*>(dst + s);   // s is 8192-aligned
    int nv = m >> 2;
    for (int k = tid; k < nv; k += blockDim.x) {
        int4 dv = d4[k];
        atomicAdd(&h[dv.x >> BSHIFT], 1);
        atomicAdd(&h[dv.y >> BSHIFT], 1);
        atomicAdd(&h[dv.z >> BSHIFT], 1);
        atomicAdd(&h[dv.w >> BSHIFT], 1);
    }
    for (int i = s + (nv << 2) + tid; i < e; i += blockDim.x)
        atomicAdd(&h[dst[i] >> BSHIFT], 1);
    __syncthreads();
    for (int b = tid; b < NB; b += blockDim.x)
        counts[(size_t)b * nchunk + c] = h[b];   // bucket-major
}

// ---------- K2: per-bucket scan over chunk counts; LAST block also scans totals->base ----------
__global__ void scanBase(int* __restrict__ counts, int* __restrict__ totals,
                         int* __restrict__ base, int* __restrict__ done,
                         int nchunk, int n_edges) {
    __shared__ int s[256];
    __shared__ int amLast;
    int b = blockIdx.x;
    int tid = threadIdx.x;      // 256
    int carry = 0;
    int* row = counts + (size_t)b * nchunk;
    for (int t0 = 0; t0 < nchunk; t0 += 256) {
        int i = t0 + tid;
        int v = (i < nchunk) ? row[i] : 0;
        s[tid] = v;
        __syncthreads();
        for (int off = 1; off < 256; off <<= 1) {
            int t = (tid >= off) ? s[tid - off] : 0;
            __syncthreads();
            s[tid] += t;
            __syncthreads();
        }
        if (i < nchunk) row[i] = s[tid] - v + carry;
        carry += s[255];
        __syncthreads();
    }
    if (tid == 0) totals[b] = carry;

    // last block scans the totals into base
    __threadfence();
    if (tid == 0) amLast = (atomicAdd(done, 1) == gridDim.x - 1);
    __syncthreads();
    if (!amLast) return;

    volatile int* vtot = (volatile int*)totals;
    int carry2 = 0;
    for (int t0 = 0; t0 < NB; t0 += 256) {
        int i = t0 + tid;
        int v = (i < NB) ? vtot[i] : 0;
        s[tid] = v;
        __syncthreads();
        for (int off = 1; off < 256; off <<= 1) {
            int t = (tid >= off) ? s[tid - off] : 0;
            __syncthreads();
            s[tid] += t;
            __syncthreads();
        }
        if (i < NB) base[i] = s[tid] - v + carry2;
        carry2 += s[255];
        __syncthreads();
    }
    if (tid == 0) base[NB] = n_edges;
}

// ---------- K3: scatter to bucket order, int4 reads + LDS-staged coalesced writes ----------
__global__ void scatter2(const int* __restrict__ src, const int* __restrict__ dst,
                         const int* __restrict__ counts, const int* __restrict__ base,
                         unsigned* __restrict__ sorted, int nchunk, int n_edges) {
    __shared__ int lcnt[NB];
    __shared__ int gb[NB];
    __shared__ int lcur[NB];
    __shared__ int scn[512];
    __shared__ unsigned sval[CHUNK];     // staged packed edges (32 KB)
    __shared__ unsigned sgad[CHUNK];     // staged global addresses (32 KB)
    int tid = threadIdx.x;               // 1024
    int c = blockIdx.x;
    int s = c * CHUNK, e = min(s + CHUNK, n_edges);

    for (int b = tid; b < NB; b += 1024) lcnt[b] = 0;
    __syncthreads();

    unsigned pv[8];
    short pb[8];
    #pragma unroll
    for (int p = 0; p < 2; p++) {
        int i0 = s + p * 4096 + tid * 4;
        if (i0 + 3 < e) {
            int4 dv = *reinterpret_cast<const int4*>(dst + i0);
            int4 sv = *reinterpret_cast<const int4*>(src + i0);
            int b0 = dv.x >> BSHIFT, b1 = dv.y >> BSHIFT,
                b2 = dv.z >> BSHIFT, b3 = dv.w >> BSHIFT;
            pv[p * 4 + 0] = ((unsigned)(dv.x & (BNODES - 1)) << 17) | (unsigned)sv.x;
            pv[p * 4 + 1] = ((unsigned)(dv.y & (BNODES - 1)) << 17) | (unsigned)sv.y;
            pv[p * 4 + 2] = ((unsigned)(dv.z & (BNODES - 1)) << 17) | (unsigned)sv.z;
            pv[p * 4 + 3] = ((unsigned)(dv.w & (BNODES - 1)) << 17) | (unsigned)sv.w;
            pb[p * 4 + 0] = (short)b0; pb[p * 4 + 1] = (short)b1;
            pb[p * 4 + 2] = (short)b2; pb[p * 4 + 3] = (short)b3;
            atomicAdd(&lcnt[b0], 1); atomicAdd(&lcnt[b1], 1);
            atomicAdd(&lcnt[b2], 1); atomicAdd(&lcnt[b3], 1);
        } else {
            #pragma unroll
            for (int j = 0; j < 4; j++) {
                int i = i0 + j;
                if (i < e) {
                    int d = dst[i];
                    int b = d >> BSHIFT;
                    pv[p * 4 + j] = ((unsigned)(d & (BNODES - 1)) << 17) | (unsigned)src[i];
                    pb[p * 4 + j] = (short)b;
                    atomicAdd(&lcnt[b], 1);
                } else pb[p * 4 + j] = -1;
            }
        }
    }
    __syncthreads();

    if (tid < 512) scn[tid] = (tid < NB) ? lcnt[tid] : 0;
    __syncthreads();
    for (int off = 1; off < 512; off <<= 1) {
        int t = 0;
        if (tid < 512 && tid >= off) t = scn[tid - off];
        __syncthreads();
        if (tid < 512) scn[tid] += t;
        __syncthreads();
    }
    if (tid < NB) {
        int excl = scn[tid] - lcnt[tid];
        lcur[tid] = excl;
        gb[tid] = base[tid] + counts[(size_t)tid * nchunk + c] - excl;
    }
    __syncthreads();

    #pragma unroll
    for (int k = 0; k < 8; k++) {
        if (pb[k] >= 0) {
            int b = pb[k];
            int q = atomicAdd(&lcur[b], 1);
            sval[q] = pv[k];
            sgad[q] = (unsigned)(gb[b] + q);
        }
    }
    __syncthreads();

    int m = e - s;
    for (int i = tid; i < m; i += 1024)
        sorted[sgad[i]] = sval[i];
}

// ---------- K4: per-bucket counting sort into LDS + fp16 gather ----------
__global__ void sortGather(const _Float16* __restrict__ feat16,
                           const unsigned* __restrict__ sorted,
                           const int* __restrict__ base,
                           unsigned* __restrict__ sorted2,   // spill path only
                           float* __restrict__ out) {
    __shared__ int cnt[BNODES];
    __shared__ int scn[BNODES];
    __shared__ int noff[BNODES + 1];
    __shared__ int cur[BNODES];
    __shared__ unsigned lsrc[LDS_CAP];
    int tid = threadIdx.x;      // 1024
    int b = blockIdx.x;

    int start = base[b];
    int cntb = base[b + 1] - start;
    bool big = (cntb > LDS_CAP);

    unsigned p0 = 0, p1 = 0, p2 = 0, p3 = 0;
    int i0 = tid, i1 = tid + 1024, i2 = tid + 2048, i3 = tid + 3072;
    if (!big) {
        if (i0 < cntb) p0 = sorted[start + i0];
        if (i1 < cntb) p1 = sorted[start + i1];
        if (i2 < cntb) p2 = sorted[start + i2];
        if (i3 < cntb) p3 = sorted[start + i3];
    }

    if (tid < BNODES) cnt[tid] = 0;
    __syncthreads();
    if (!big) {
        if (i0 < cntb) atomicAdd(&cnt[(p0 >> 17) & (BNODES - 1)], 1);
        if (i1 < cntb) atomicAdd(&cnt[(p1 >> 17) & (BNODES - 1)], 1);
        if (i2 < cntb) atomicAdd(&cnt[(p2 >> 17) & (BNODES - 1)], 1);
        if (i3 < cntb) atomicAdd(&cnt[(p3 >> 17) & (BNODES - 1)], 1);
    } else {
        for (int i = tid; i < cntb; i += 1024)
            atomicAdd(&cnt[(sorted[start + i] >> 17) & (BNODES - 1)], 1);
    }
    __syncthreads();

    int v = (tid < BNODES) ? cnt[tid] : 0;
    if (tid < BNODES) scn[tid] = v;
    __syncthreads();
    for (int off = 1; off < BNODES; off <<= 1) {
        int t = 0;
        if (tid < BNODES && tid >= off) t = scn[tid - off];
        __syncthreads();
        if (tid < BNODES) scn[tid] += t;
        __syncthreads();
    }
    if (tid < BNODES) { noff[tid] = scn[tid] - v; cur[tid] = scn[tid] - v; }
    if (tid == 0) noff[BNODES] = cntb;
    __syncthreads();

    if (!big) {
        if (i0 < cntb) { int q = atomicAdd(&cur[(p0 >> 17) & (BNODES - 1)], 1); lsrc[q] = p0 & 0x1FFFF; }
        if (i1 < cntb) { int q = atomicAdd(&cur[(p1 >> 17) & (BNODES - 1)], 1); lsrc[q] = p1 & 0x1FFFF; }
        if (i2 < cntb) { int q = atomicAdd(&cur[(p2 >> 17) & (BNODES - 1)], 1); lsrc[q] = p2 & 0x1FFFF; }
        if (i3 < cntb) { int q = atomicAdd(&cur[(p3 >> 17) & (BNODES - 1)], 1); lsrc[q] = p3 & 0x1FFFF; }
    } else {
        for (int i = tid; i < cntb; i += 1024) {
            unsigned p = sorted[start + i];
            int q = atomicAdd(&cur[(p >> 17) & (BNODES - 1)], 1);
            sorted2[start + q] = p & 0x1FFFF;
        }
    }
    __syncthreads();

    int g = tid >> 3, gl = tid & 7;
    for (int n = g; n < BNODES; n += 128) {
        int node = (b << BSHIFT) + n;
        if (node >= N_NODES) break;
        int off = noff[n], endn = noff[n + 1];
        int deg = endn - off;
        float4 accA = make_float4(0.f, 0.f, 0.f, 0.f);
        float4 accB = make_float4(0.f, 0.f, 0.f, 0.f);
        int e = off;
        if (!big) {
            for (; e + 4 <= endn; e += 4) {
                int s0 = lsrc[e], s1 = lsrc[e + 1], s2 = lsrc[e + 2], s3 = lsrc[e + 3];
                half8 v0 = *reinterpret_cast<const half8*>(&feat16[(size_t)s0 * D + gl * 8]);
                half8 v1 = *reinterpret_cast<const half8*>(&feat16[(size_t)s1 * D + gl * 8]);
                half8 v2 = *reinterpret_cast<const half8*>(&feat16[(size_t)s2 * D + gl * 8]);
                half8 v3 = *reinterpret_cast<const half8*>(&feat16[(size_t)s3 * D + gl * 8]);
                accA.x += (float)v0[0] + (float)v1[0] + (float)v2[0] + (float)v3[0];
                accA.y += (float)v0[1] + (float)v1[1] + (float)v2[1] + (float)v3[1];
                accA.z += (float)v0[2] + (float)v1[2] + (float)v2[2] + (float)v3[2];
                accA.w += (float)v0[3] + (float)v1[3] + (float)v2[3] + (float)v3[3];
                accB.x += (float)v0[4] + (float)v1[4] + (float)v2[4] + (float)v3[4];
                accB.y += (float)v0[5] + (float)v1[5] + (float)v2[5] + (float)v3[5];
                accB.z += (float)v0[6] + (float)v1[6] + (float)v2[6] + (float)v3[6];
                accB.w += (float)v0[7] + (float)v1[7] + (float)v2[7] + (float)v3[7];
            }
            for (; e < endn; e++) {
                int s = lsrc[e];
                half8 vv = *reinterpret_cast<const half8*>(&feat16[(size_t)s * D + gl * 8]);
                accA.x += (float)vv[0]; accA.y += (float)vv[1];
                accA.z += (float)vv[2]; accA.w += (float)vv[3];
                accB.x += (float)vv[4]; accB.y += (float)vv[5];
                accB.z += (float)vv[6]; accB.w += (float)vv[7];
            }
        } else {
            for (; e < endn; e++) {
                int s = (int)sorted2[start + e];
                half8 vv = *reinterpret_cast<const half8*>(&feat16[(size_t)s * D + gl * 8]);
                accA.x += (float)vv[0]; accA.y += (float)vv[1];
                accA.z += (float)vv[2]; accA.w += (float)vv[3];
                accB.x += (float)vv[4]; accB.y += (float)vv[5];
                accB.z += (float)vv[6]; accB.w += (float)vv[7];
            }
        }
        float inv = (deg > 0) ? 1.0f / (float)deg : 0.0f;
        float4 oA = make_float4(accA.x * inv, accA.y * inv, accA.z * inv, accA.w * inv);
        float4 oB = make_float4(accB.x * inv, accB.y * inv, accB.z * inv, accB.w * inv);
        float* orow = &out[(size_t)node * D + gl * 8];
        *reinterpret_cast<float4*>(orow) = oA;
        *reinterpret_cast<float4*>(orow + 4) = oB;
    }
}

// ---------- fallback (atomic scatter) if ws too small ----------
__global__ void gcn_scatter(const float* __restrict__ feat, const int* __restrict__ src,
                            const int* __restrict__ dst, float* __restrict__ out,
                            float* __restrict__ deg, int n_edges) {
    long long gtid = (long long)blockIdx.x * blockDim.x + threadIdx.x;
    int edge = (int)(gtid >> 6);
    int lane = threadIdx.x & 63;
    if (edge >= n_edges) return;
    atomicAdd(&out[(long long)dst[edge] * D + lane],
              feat[(long long)src[edge] * D + lane]);
    if (lane == 0) atomicAdd(&deg[dst[edge]], 1.0f);
}
__global__ void gcn_finalize(float* __restrict__ out, const float* __restrict__ deg,
                             int total) {
    int i = blockIdx.x * blockDim.x + threadIdx.x;
    if (i >= total) return;
    float dg = deg[i >> 6];
    out[i] = (dg > 0.0f) ? out[i] / dg : 0.0f;
}

extern "C" void kernel_launch(void* const* d_in, const int* in_sizes, int n_in,
                              void* d_out, int out_size, void* d_ws, size_t ws_size,
                              hipStream_t stream) {
    const float* feat = (const float*)d_in[0];
    const int* src = (const int*)d_in[1];
    const int* dst = (const int*)d_in[2];
    float* out = (float*)d_out;
    int n_edges = in_sizes[1];

    int nchunk = (n_edges + CHUNK - 1) / CHUNK;
    size_t ncounts = (size_t)NB * nchunk;
    size_t f16_bytes = (size_t)N_NODES * D * sizeof(_Float16);   // 12.8 MB
    size_t need = f16_bytes + (ncounts + NB + NB + 1 + 1) * sizeof(int)
                + (size_t)n_edges * 2 * sizeof(unsigned);

    if (ws_size < need) {
        float* deg = (float*)d_ws;
        int total = N_NODES * D;
        hipMemsetAsync(out, 0, (size_t)total * sizeof(float), stream);
        hipMemsetAsync(deg, 0, (size_t)N_NODES * sizeof(float), stream);
        long long threads = (long long)n_edges * 64;
        int grid = (int)((threads + 255) / 256);
        gcn_scatter<<<grid, 256, 0, stream>>>(feat, src, dst, out, deg, n_edges);
        gcn_finalize<<<(total + 255) / 256, 256, 0, stream>>>(out, deg, total);
        return;
    }

    char* wp = (char*)d_ws;
    _Float16* feat16 = (_Float16*)wp;            wp += f16_bytes;
    int* counts = (int*)wp;                      wp += ncounts * sizeof(int);
    int* totals = (int*)wp;                      wp += (size_t)NB * sizeof(int);
    int* base = (int*)wp;                        wp += (size_t)(NB + 1) * sizeof(int);
    int* done = (int*)wp;                        wp += sizeof(int);
    unsigned* sorted = (unsigned*)wp;            wp += (size_t)n_edges * sizeof(unsigned);
    unsigned* sorted2 = (unsigned*)wp;           // spill path only

    int n4pairs = N_NODES * D / 8;
    int chgrid = nchunk + 256;                   // hist blocks + 256 dedicated conv blocks
    convhist<<<chgrid, 1024, 0, stream>>>((const float4*)feat, (float4*)feat16,
                                          n4pairs, dst, counts, done, nchunk, n_edges);
    scanBase<<<NB, 256, 0, stream>>>(counts, totals, base, done, nchunk, n_edges);
    scatter2<<<nchunk, 1024, 0, stream>>>(src, dst, counts, base, sorted,
                                          nchunk, n_edges);
    sortGather<<<NB, 1024, 0, stream>>>(feat16, sorted, base, sorted2, out);
}

// Round 19
// 58.620 us; speedup vs baseline: 1.5236x; 1.4391x over previous
//
#include <hip/hip_runtime.h>
#include <hip/hip_bf16.h>

#define N_NODES 100000
#define D 64
#define BSHIFT 8
#define BNODES 256        // nodes per bucket
#define NB 391            // ceil(100000/256)
#define CHUNK 8192
#define LDS_CAP 4096      // edges per bucket in LDS (mean 3200, sd ~56)

typedef __attribute__((ext_vector_type(8))) _Float16 half8;

// ---------- K1: role-split — hist blocks (int4 reads) / conv-only blocks ----------
// Also zeroes the `done` counter consumed by scanBase (kernel-boundary ordered).
__global__ void convhist(const float4* __restrict__ feat4, float4* __restrict__ feat16,
                         int n4pairs, const int* __restrict__ dst, int* __restrict__ counts,
                         int* __restrict__ done, int nchunk, int n_edges) {
    int c = blockIdx.x;
    if (c == 0 && threadIdx.x == 0) *done = 0;
    if (c >= nchunk) {
        int nb = gridDim.x - nchunk;
        int bi = c - nchunk;
        for (int i = bi * blockDim.x + threadIdx.x; i < n4pairs; i += nb * blockDim.x) {
            float4 a = feat4[i * 2];
            float4 b = feat4[i * 2 + 1];
            half8 h;
            h[0] = (_Float16)a.x; h[1] = (_Float16)a.y;
            h[2] = (_Float16)a.z; h[3] = (_Float16)a.w;
            h[4] = (_Float16)b.x; h[5] = (_Float16)b.y;
            h[6] = (_Float16)b.z; h[7] = (_Float16)b.w;
            *reinterpret_cast<half8*>(&feat16[i]) = h;
        }
        return;
    }
    __shared__ int h[NB];
    int tid = threadIdx.x;
    for (int i = tid; i < NB; i += blockDim.x) h[i] = 0;
    __syncthreads();
    int s = c * CHUNK, e = min(s + CHUNK, n_edges);
    int m = e - s;
    const int4* d4 = reinterpret_cast<const int4*>(dst + s);   // s is 8192-aligned
    int nv = m >> 2;
    for (int k = tid; k < nv; k += blockDim.x) {
        int4 dv = d4[k];
        atomicAdd(&h[dv.x >> BSHIFT], 1);
        atomicAdd(&h[dv.y >> BSHIFT], 1);
        atomicAdd(&h[dv.z >> BSHIFT], 1);
        atomicAdd(&h[dv.w >> BSHIFT], 1);
    }
    for (int i = s + (nv << 2) + tid; i < e; i += blockDim.x)
        atomicAdd(&h[dst[i] >> BSHIFT], 1);
    __syncthreads();
    for (int b = tid; b < NB; b += blockDim.x)
        counts[(size_t)b * nchunk + c] = h[b];   // bucket-major
}

// ---------- K2: per-bucket scan; LAST block scans totals->base (atomics only, no fence) ----------
__global__ void scanBase(int* __restrict__ counts, int* __restrict__ totals,
                         int* __restrict__ base, int* __restrict__ done,
                         int nchunk, int n_edges) {
    __shared__ int s[256];
    __shared__ int amLast;
    int b = blockIdx.x;
    int tid = threadIdx.x;      // 256
    int carry = 0;
    int* row = counts + (size_t)b * nchunk;
    for (int t0 = 0; t0 < nchunk; t0 += 256) {
        int i = t0 + tid;
        int v = (i < nchunk) ? row[i] : 0;
        s[tid] = v;
        __syncthreads();
        for (int off = 1; off < 256; off <<= 1) {
            int t = (tid >= off) ? s[tid - off] : 0;
            __syncthreads();
            s[tid] += t;
            __syncthreads();
        }
        if (i < nchunk) row[i] = s[tid] - v + carry;
        carry += s[255];
        __syncthreads();
    }

    if (tid == 0) {
        // publish total via device-scope atomic (memory-side coherent point)
        int old = atomicExch(&totals[b], carry);
        asm volatile("s_waitcnt vmcnt(0)" :: "v"(old) : "memory");  // exch complete before signaling
        amLast = (atomicAdd(done, 1) == (int)gridDim.x - 1);
    }
    __syncthreads();
    if (!amLast) return;

    // coherent reads of all totals, then exclusive scan -> base
    int carry2 = 0;
    for (int t0 = 0; t0 < NB; t0 += 256) {
        int i = t0 + tid;
        int v = (i < NB) ? atomicOr(&totals[i], 0) : 0;
        s[tid] = v;
        __syncthreads();
        for (int off = 1; off < 256; off <<= 1) {
            int t = (tid >= off) ? s[tid - off] : 0;
            __syncthreads();
            s[tid] += t;
            __syncthreads();
        }
        if (i < NB) base[i] = s[tid] - v + carry2;
        carry2 += s[255];
        __syncthreads();
    }
    if (tid == 0) base[NB] = n_edges;
}

// ---------- K3: scatter to bucket order, int4 reads + LDS-staged coalesced writes ----------
__global__ void scatter2(const int* __restrict__ src, const int* __restrict__ dst,
                         const int* __restrict__ counts, const int* __restrict__ base,
                         unsigned* __restrict__ sorted, int nchunk, int n_edges) {
    __shared__ int lcnt[NB];
    __shared__ int gb[NB];
    __shared__ int lcur[NB];
    __shared__ int scn[512];
    __shared__ unsigned sval[CHUNK];     // staged packed edges (32 KB)
    __shared__ unsigned sgad[CHUNK];     // staged global addresses (32 KB)
    int tid = threadIdx.x;               // 1024
    int c = blockIdx.x;
    int s = c * CHUNK, e = min(s + CHUNK, n_edges);

    for (int b = tid; b < NB; b += 1024) lcnt[b] = 0;
    __syncthreads();

    unsigned pv[8];
    short pb[8];
    #pragma unroll
    for (int p = 0; p < 2; p++) {
        int i0 = s + p * 4096 + tid * 4;
        if (i0 + 3 < e) {
            int4 dv = *reinterpret_cast<const int4*>(dst + i0);
            int4 sv = *reinterpret_cast<const int4*>(src + i0);
            int b0 = dv.x >> BSHIFT, b1 = dv.y >> BSHIFT,
                b2 = dv.z >> BSHIFT, b3 = dv.w >> BSHIFT;
            pv[p * 4 + 0] = ((unsigned)(dv.x & (BNODES - 1)) << 17) | (unsigned)sv.x;
            pv[p * 4 + 1] = ((unsigned)(dv.y & (BNODES - 1)) << 17) | (unsigned)sv.y;
            pv[p * 4 + 2] = ((unsigned)(dv.z & (BNODES - 1)) << 17) | (unsigned)sv.z;
            pv[p * 4 + 3] = ((unsigned)(dv.w & (BNODES - 1)) << 17) | (unsigned)sv.w;
            pb[p * 4 + 0] = (short)b0; pb[p * 4 + 1] = (short)b1;
            pb[p * 4 + 2] = (short)b2; pb[p * 4 + 3] = (short)b3;
            atomicAdd(&lcnt[b0], 1); atomicAdd(&lcnt[b1], 1);
            atomicAdd(&lcnt[b2], 1); atomicAdd(&lcnt[b3], 1);
        } else {
            #pragma unroll
            for (int j = 0; j < 4; j++) {
                int i = i0 + j;
                if (i < e) {
                    int d = dst[i];
                    int b = d >> BSHIFT;
                    pv[p * 4 + j] = ((unsigned)(d & (BNODES - 1)) << 17) | (unsigned)src[i];
                    pb[p * 4 + j] = (short)b;
                    atomicAdd(&lcnt[b], 1);
                } else pb[p * 4 + j] = -1;
            }
        }
    }
    __syncthreads();

    if (tid < 512) scn[tid] = (tid < NB) ? lcnt[tid] : 0;
    __syncthreads();
    for (int off = 1; off < 512; off <<= 1) {
        int t = 0;
        if (tid < 512 && tid >= off) t = scn[tid - off];
        __syncthreads();
        if (tid < 512) scn[tid] += t;
        __syncthreads();
    }
    if (tid < NB) {
        int excl = scn[tid] - lcnt[tid];
        lcur[tid] = excl;
        gb[tid] = base[tid] + counts[(size_t)tid * nchunk + c] - excl;
    }
    __syncthreads();

    #pragma unroll
    for (int k = 0; k < 8; k++) {
        if (pb[k] >= 0) {
            int b = pb[k];
            int q = atomicAdd(&lcur[b], 1);
            sval[q] = pv[k];
            sgad[q] = (unsigned)(gb[b] + q);
        }
    }
    __syncthreads();

    int m = e - s;
    for (int i = tid; i < m; i += 1024)
        sorted[sgad[i]] = sval[i];
}

// ---------- K4: per-bucket counting sort into LDS + fp16 gather ----------
__global__ void sortGather(const _Float16* __restrict__ feat16,
                           const unsigned* __restrict__ sorted,
                           const int* __restrict__ base,
                           unsigned* __restrict__ sorted2,   // spill path only
                           float* __restrict__ out) {
    __shared__ int cnt[BNODES];
    __shared__ int scn[BNODES];
    __shared__ int noff[BNODES + 1];
    __shared__ int cur[BNODES];
    __shared__ unsigned lsrc[LDS_CAP];
    int tid = threadIdx.x;      // 1024
    int b = blockIdx.x;

    int start = base[b];
    int cntb = base[b + 1] - start;
    bool big = (cntb > LDS_CAP);

    unsigned p0 = 0, p1 = 0, p2 = 0, p3 = 0;
    int i0 = tid, i1 = tid + 1024, i2 = tid + 2048, i3 = tid + 3072;
    if (!big) {
        if (i0 < cntb) p0 = sorted[start + i0];
        if (i1 < cntb) p1 = sorted[start + i1];
        if (i2 < cntb) p2 = sorted[start + i2];
        if (i3 < cntb) p3 = sorted[start + i3];
    }

    if (tid < BNODES) cnt[tid] = 0;
    __syncthreads();
    if (!big) {
        if (i0 < cntb) atomicAdd(&cnt[(p0 >> 17) & (BNODES - 1)], 1);
        if (i1 < cntb) atomicAdd(&cnt[(p1 >> 17) & (BNODES - 1)], 1);
        if (i2 < cntb) atomicAdd(&cnt[(p2 >> 17) & (BNODES - 1)], 1);
        if (i3 < cntb) atomicAdd(&cnt[(p3 >> 17) & (BNODES - 1)], 1);
    } else {
        for (int i = tid; i < cntb; i += 1024)
            atomicAdd(&cnt[(sorted[start + i] >> 17) & (BNODES - 1)], 1);
    }
    __syncthreads();

    int v = (tid < BNODES) ? cnt[tid] : 0;
    if (tid < BNODES) scn[tid] = v;
    __syncthreads();
    for (int off = 1; off < BNODES; off <<= 1) {
        int t = 0;
        if (tid < BNODES && tid >= off) t = scn[tid - off];
        __syncthreads();
        if (tid < BNODES) scn[tid] += t;
        __syncthreads();
    }
    if (tid < BNODES) { noff[tid] = scn[tid] - v; cur[tid] = scn[tid] - v; }
    if (tid == 0) noff[BNODES] = cntb;
    __syncthreads();

    if (!big) {
        if (i0 < cntb) { int q = atomicAdd(&cur[(p0 >> 17) & (BNODES - 1)], 1); lsrc[q] = p0 & 0x1FFFF; }
        if (i1 < cntb) { int q = atomicAdd(&cur[(p1 >> 17) & (BNODES - 1)], 1); lsrc[q] = p1 & 0x1FFFF; }
        if (i2 < cntb) { int q = atomicAdd(&cur[(p2 >> 17) & (BNODES - 1)], 1); lsrc[q] = p2 & 0x1FFFF; }
        if (i3 < cntb) { int q = atomicAdd(&cur[(p3 >> 17) & (BNODES - 1)], 1); lsrc[q] = p3 & 0x1FFFF; }
    } else {
        for (int i = tid; i < cntb; i += 1024) {
            unsigned p = sorted[start + i];
            int q = atomicAdd(&cur[(p >> 17) & (BNODES - 1)], 1);
            sorted2[start + q] = p & 0x1FFFF;
        }
    }
    __syncthreads();

    int g = tid >> 3, gl = tid & 7;
    for (int n = g; n < BNODES; n += 128) {
        int node = (b << BSHIFT) + n;
        if (node >= N_NODES) break;
        int off = noff[n], endn = noff[n + 1];
        int deg = endn - off;
        float4 accA = make_float4(0.f, 0.f, 0.f, 0.f);
        float4 accB = make_float4(0.f, 0.f, 0.f, 0.f);
        int e = off;
        if (!big) {
            for (; e + 4 <= endn; e += 4) {
                int s0 = lsrc[e], s1 = lsrc[e + 1], s2 = lsrc[e + 2], s3 = lsrc[e + 3];
                half8 v0 = *reinterpret_cast<const half8*>(&feat16[(size_t)s0 * D + gl * 8]);
                half8 v1 = *reinterpret_cast<const half8*>(&feat16[(size_t)s1 * D + gl * 8]);
                half8 v2 = *reinterpret_cast<const half8*>(&feat16[(size_t)s2 * D + gl * 8]);
                half8 v3 = *reinterpret_cast<const half8*>(&feat16[(size_t)s3 * D + gl * 8]);
                accA.x += (float)v0[0] + (float)v1[0] + (float)v2[0] + (float)v3[0];
                accA.y += (float)v0[1] + (float)v1[1] + (float)v2[1] + (float)v3[1];
                accA.z += (float)v0[2] + (float)v1[2] + (float)v2[2] + (float)v3[2];
                accA.w += (float)v0[3] + (float)v1[3] + (float)v2[3] + (float)v3[3];
                accB.x += (float)v0[4] + (float)v1[4] + (float)v2[4] + (float)v3[4];
                accB.y += (float)v0[5] + (float)v1[5] + (float)v2[5] + (float)v3[5];
                accB.z += (float)v0[6] + (float)v1[6] + (float)v2[6] + (float)v3[6];
                accB.w += (float)v0[7] + (float)v1[7] + (float)v2[7] + (float)v3[7];
            }
            for (; e < endn; e++) {
                int s = lsrc[e];
                half8 vv = *reinterpret_cast<const half8*>(&feat16[(size_t)s * D + gl * 8]);
                accA.x += (float)vv[0]; accA.y += (float)vv[1];
                accA.z += (float)vv[2]; accA.w += (float)vv[3];
                accB.x += (float)vv[4]; accB.y += (float)vv[5];
                accB.z += (float)vv[6]; accB.w += (float)vv[7];
            }
        } else {
            for (; e < endn; e++) {
                int s = (int)sorted2[start + e];
                half8 vv = *reinterpret_cast<const half8*>(&feat16[(size_t)s * D + gl * 8]);
                accA.x += (float)vv[0]; accA.y += (float)vv[1];
                accA.z += (float)vv[2]; accA.w += (float)vv[3];
                accB.x += (float)vv[4]; accB.y += (float)vv[5];
                accB.z += (float)vv[6]; accB.w += (float)vv[7];
            }
        }
        float inv = (deg > 0) ? 1.0f / (float)deg : 0.0f;
        float4 oA = make_float4(accA.x * inv, accA.y * inv, accA.z * inv, accA.w * inv);
        float4 oB = make_float4(accB.x * inv, accB.y * inv, accB.z * inv, accB.w * inv);
        float* orow = &out[(size_t)node * D + gl * 8];
        *reinterpret_cast<float4*>(orow) = oA;
        *reinterpret_cast<float4*>(orow + 4) = oB;
    }
}

// ---------- fallback (atomic scatter) if ws too small ----------
__global__ void gcn_scatter(const float* __restrict__ feat, const int* __restrict__ src,
                            const int* __restrict__ dst, float* __restrict__ out,
                            float* __restrict__ deg, int n_edges) {
    long long gtid = (long long)blockIdx.x * blockDim.x + threadIdx.x;
    int edge = (int)(gtid >> 6);
    int lane = threadIdx.x & 63;
    if (edge >= n_edges) return;
    atomicAdd(&out[(long long)dst[edge] * D + lane],
              feat[(long long)src[edge] * D + lane]);
    if (lane == 0) atomicAdd(&deg[dst[edge]], 1.0f);
}
__global__ void gcn_finalize(float* __restrict__ out, const float* __restrict__ deg,
                             int total) {
    int i = blockIdx.x * blockDim.x + threadIdx.x;
    if (i >= total) return;
    float dg = deg[i >> 6];
    out[i] = (dg > 0.0f) ? out[i] / dg : 0.0f;
}

extern "C" void kernel_launch(void* const* d_in, const int* in_sizes, int n_in,
                              void* d_out, int out_size, void* d_ws, size_t ws_size,
                              hipStream_t stream) {
    const float* feat = (const float*)d_in[0];
    const int* src = (const int*)d_in[1];
    const int* dst = (const int*)d_in[2];
    float* out = (float*)d_out;
    int n_edges = in_sizes[1];

    int nchunk = (n_edges + CHUNK - 1) / CHUNK;
    size_t ncounts = (size_t)NB * nchunk;
    size_t f16_bytes = (size_t)N_NODES * D * sizeof(_Float16);   // 12.8 MB
    size_t need = f16_bytes + (ncounts + NB + NB + 1 + 1) * sizeof(int)
                + (size_t)n_edges * 2 * sizeof(unsigned);

    if (ws_size < need) {
        float* deg = (float*)d_ws;
        int total = N_NODES * D;
        hipMemsetAsync(out, 0, (size_t)total * sizeof(float), stream);
        hipMemsetAsync(deg, 0, (size_t)N_NODES * sizeof(float), stream);
        long long threads = (long long)n_edges * 64;
        int grid = (int)((threads + 255) / 256);
        gcn_scatter<<<grid, 256, 0, stream>>>(feat, src, dst, out, deg, n_edges);
        gcn_finalize<<<(total + 255) / 256, 256, 0, stream>>>(out, deg, total);
        return;
    }

    char* wp = (char*)d_ws;
    _Float16* feat16 = (_Float16*)wp;            wp += f16_bytes;
    int* counts = (int*)wp;                      wp += ncounts * sizeof(int);
    int* totals = (int*)wp;                      wp += (size_t)NB * sizeof(int);
    int* base = (int*)wp;                        wp += (size_t)(NB + 1) * sizeof(int);
    int* done = (int*)wp;                        wp += sizeof(int);
    unsigned* sorted = (unsigned*)wp;            wp += (size_t)n_edges * sizeof(unsigned);
    unsigned* sorted2 = (unsigned*)wp;           // spill path only

    int n4pairs = N_NODES * D / 8;
    int chgrid = nchunk + 256;                   // hist blocks + 256 dedicated conv blocks
    convhist<<<chgrid, 1024, 0, stream>>>((const float4*)feat, (float4*)feat16,
                                          n4pairs, dst, counts, done, nchunk, n_edges);
    scanBase<<<NB, 256, 0, stream>>>(counts, totals, base, done, nchunk, n_edges);
    scatter2<<<nchunk, 1024, 0, stream>>>(src, dst, counts, base, sorted,
                                          nchunk, n_edges);
    sortGather<<<NB, 1024, 0, stream>>>(feat16, sorted, base, sorted2, out);
}

// Round 20
// 54.450 us; speedup vs baseline: 1.6403x; 1.0766x over previous
//
#include <hip/hip_runtime.h>
#include <hip/hip_bf16.h>

#define N_NODES 100000
#define D 64
#define BSHIFT 8
#define BNODES 256        // nodes per bucket
#define NB 391            // ceil(100000/256)
#define CHUNK 8192
#define LDS_CAP 4096      // edges per bucket in LDS (mean 3200, sd ~56)

typedef __attribute__((ext_vector_type(8))) _Float16 half8;

// ---------- K1: role-split — hist blocks (int4 reads) / conv-only blocks ----------
__global__ void convhist(const float4* __restrict__ feat4, float4* __restrict__ feat16,
                         int n4pairs, const int* __restrict__ dst, int* __restrict__ counts,
                         int nchunk, int n_edges) {
    int c = blockIdx.x;
    if (c >= nchunk) {
        int nb = gridDim.x - nchunk;
        int bi = c - nchunk;
        for (int i = bi * blockDim.x + threadIdx.x; i < n4pairs; i += nb * blockDim.x) {
            float4 a = feat4[i * 2];
            float4 b = feat4[i * 2 + 1];
            half8 h;
            h[0] = (_Float16)a.x; h[1] = (_Float16)a.y;
            h[2] = (_Float16)a.z; h[3] = (_Float16)a.w;
            h[4] = (_Float16)b.x; h[5] = (_Float16)b.y;
            h[6] = (_Float16)b.z; h[7] = (_Float16)b.w;
            *reinterpret_cast<half8*>(&feat16[i]) = h;
        }
        return;
    }
    __shared__ int h[NB];
    int tid = threadIdx.x;
    for (int i = tid; i < NB; i += blockDim.x) h[i] = 0;
    __syncthreads();
    int s = c * CHUNK, e = min(s + CHUNK, n_edges);
    int m = e - s;
    const int4* d4 = reinterpret_cast<const int4*>(dst + s);   // s is 8192-aligned
    int nv = m >> 2;
    for (int k = tid; k < nv; k += blockDim.x) {
        int4 dv = d4[k];
        atomicAdd(&h[dv.x >> BSHIFT], 1);
        atomicAdd(&h[dv.y >> BSHIFT], 1);
        atomicAdd(&h[dv.z >> BSHIFT], 1);
        atomicAdd(&h[dv.w >> BSHIFT], 1);
    }
    for (int i = s + (nv << 2) + tid; i < e; i += blockDim.x)
        atomicAdd(&h[dst[i] >> BSHIFT], 1);
    __syncthreads();
    for (int b = tid; b < NB; b += blockDim.x)
        counts[(size_t)b * nchunk + c] = h[b];   // bucket-major
}

// ---------- K2: per-bucket exclusive scan over chunk counts ----------
__global__ void scanB(int* __restrict__ counts, int* __restrict__ totals, int nchunk) {
    __shared__ int s[256];
    int b = blockIdx.x;
    int tid = threadIdx.x;
    int carry = 0;
    int* row = counts + (size_t)b * nchunk;
    for (int t0 = 0; t0 < nchunk; t0 += 256) {
        int i = t0 + tid;
        int v = (i < nchunk) ? row[i] : 0;
        s[tid] = v;
        __syncthreads();
        for (int off = 1; off < 256; off <<= 1) {
            int t = (tid >= off) ? s[tid - off] : 0;
            __syncthreads();
            s[tid] += t;
            __syncthreads();
        }
        if (i < nchunk) row[i] = s[tid] - v + carry;
        carry += s[255];
        __syncthreads();
    }
    if (tid == 0) totals[b] = carry;
}

// ---------- K2b: exclusive scan of totals -> bucket base (one block, NB<=1024) ----------
__global__ void baseK(const int* __restrict__ totals, int* __restrict__ base,
                      int n_edges) {
    __shared__ int s[1024];
    int tid = threadIdx.x;
    int v = (tid < NB) ? totals[tid] : 0;
    s[tid] = v;
    __syncthreads();
    for (int off = 1; off < 1024; off <<= 1) {
        int t = (tid >= off) ? s[tid - off] : 0;
        __syncthreads();
        s[tid] += t;
        __syncthreads();
    }
    if (tid < NB) base[tid] = s[tid] - v;
    if (tid == 0) base[NB] = n_edges;
}

// ---------- K3: scatter to bucket order, int4 reads + LDS-staged coalesced writes ----------
__global__ void scatter2(const int* __restrict__ src, const int* __restrict__ dst,
                         const int* __restrict__ counts, const int* __restrict__ base,
                         unsigned* __restrict__ sorted, int nchunk, int n_edges) {
    __shared__ int lcnt[NB];
    __shared__ int gb[NB];
    __shared__ int lcur[NB];
    __shared__ int scn[512];
    __shared__ unsigned sval[CHUNK];     // staged packed edges (32 KB)
    __shared__ unsigned sgad[CHUNK];     // staged global addresses (32 KB)
    int tid = threadIdx.x;               // 1024
    int c = blockIdx.x;
    int s = c * CHUNK, e = min(s + CHUNK, n_edges);

    for (int b = tid; b < NB; b += 1024) lcnt[b] = 0;
    __syncthreads();

    unsigned pv[8];
    short pb[8];
    #pragma unroll
    for (int p = 0; p < 2; p++) {
        int i0 = s + p * 4096 + tid * 4;
        if (i0 + 3 < e) {
            int4 dv = *reinterpret_cast<const int4*>(dst + i0);
            int4 sv = *reinterpret_cast<const int4*>(src + i0);
            int b0 = dv.x >> BSHIFT, b1 = dv.y >> BSHIFT,
                b2 = dv.z >> BSHIFT, b3 = dv.w >> BSHIFT;
            pv[p * 4 + 0] = ((unsigned)(dv.x & (BNODES - 1)) << 17) | (unsigned)sv.x;
            pv[p * 4 + 1] = ((unsigned)(dv.y & (BNODES - 1)) << 17) | (unsigned)sv.y;
            pv[p * 4 + 2] = ((unsigned)(dv.z & (BNODES - 1)) << 17) | (unsigned)sv.z;
            pv[p * 4 + 3] = ((unsigned)(dv.w & (BNODES - 1)) << 17) | (unsigned)sv.w;
            pb[p * 4 + 0] = (short)b0; pb[p * 4 + 1] = (short)b1;
            pb[p * 4 + 2] = (short)b2; pb[p * 4 + 3] = (short)b3;
            atomicAdd(&lcnt[b0], 1); atomicAdd(&lcnt[b1], 1);
            atomicAdd(&lcnt[b2], 1); atomicAdd(&lcnt[b3], 1);
        } else {
            #pragma unroll
            for (int j = 0; j < 4; j++) {
                int i = i0 + j;
                if (i < e) {
                    int d = dst[i];
                    int b = d >> BSHIFT;
                    pv[p * 4 + j] = ((unsigned)(d & (BNODES - 1)) << 17) | (unsigned)src[i];
                    pb[p * 4 + j] = (short)b;
                    atomicAdd(&lcnt[b], 1);
                } else pb[p * 4 + j] = -1;
            }
        }
    }
    __syncthreads();

    if (tid < 512) scn[tid] = (tid < NB) ? lcnt[tid] : 0;
    __syncthreads();
    for (int off = 1; off < 512; off <<= 1) {
        int t = 0;
        if (tid < 512 && tid >= off) t = scn[tid - off];
        __syncthreads();
        if (tid < 512) scn[tid] += t;
        __syncthreads();
    }
    if (tid < NB) {
        int excl = scn[tid] - lcnt[tid];
        lcur[tid] = excl;
        gb[tid] = base[tid] + counts[(size_t)tid * nchunk + c] - excl;
    }
    __syncthreads();

    #pragma unroll
    for (int k = 0; k < 8; k++) {
        if (pb[k] >= 0) {
            int b = pb[k];
            int q = atomicAdd(&lcur[b], 1);
            sval[q] = pv[k];
            sgad[q] = (unsigned)(gb[b] + q);
        }
    }
    __syncthreads();

    int m = e - s;
    for (int i = tid; i < m; i += 1024)
        sorted[sgad[i]] = sval[i];
}

// ---------- K4: per-bucket counting sort into LDS + fp16 gather ----------
__global__ void sortGather(const _Float16* __restrict__ feat16,
                           const unsigned* __restrict__ sorted,
                           const int* __restrict__ base,
                           unsigned* __restrict__ sorted2,   // spill path only
                           float* __restrict__ out) {
    __shared__ int cnt[BNODES];
    __shared__ int scn[BNODES];
    __shared__ int noff[BNODES + 1];
    __shared__ int cur[BNODES];
    __shared__ unsigned lsrc[LDS_CAP];
    int tid = threadIdx.x;      // 1024
    int b = blockIdx.x;

    int start = base[b];
    int cntb = base[b + 1] - start;
    bool big = (cntb > LDS_CAP);

    unsigned p0 = 0, p1 = 0, p2 = 0, p3 = 0;
    int i0 = tid, i1 = tid + 1024, i2 = tid + 2048, i3 = tid + 3072;
    if (!big) {
        if (i0 < cntb) p0 = sorted[start + i0];
        if (i1 < cntb) p1 = sorted[start + i1];
        if (i2 < cntb) p2 = sorted[start + i2];
        if (i3 < cntb) p3 = sorted[start + i3];
    }

    if (tid < BNODES) cnt[tid] = 0;
    __syncthreads();
    if (!big) {
        if (i0 < cntb) atomicAdd(&cnt[(p0 >> 17) & (BNODES - 1)], 1);
        if (i1 < cntb) atomicAdd(&cnt[(p1 >> 17) & (BNODES - 1)], 1);
        if (i2 < cntb) atomicAdd(&cnt[(p2 >> 17) & (BNODES - 1)], 1);
        if (i3 < cntb) atomicAdd(&cnt[(p3 >> 17) & (BNODES - 1)], 1);
    } else {
        for (int i = tid; i < cntb; i += 1024)
            atomicAdd(&cnt[(sorted[start + i] >> 17) & (BNODES - 1)], 1);
    }
    __syncthreads();

    int v = (tid < BNODES) ? cnt[tid] : 0;
    if (tid < BNODES) scn[tid] = v;
    __syncthreads();
    for (int off = 1; off < BNODES; off <<= 1) {
        int t = 0;
        if (tid < BNODES && tid >= off) t = scn[tid - off];
        __syncthreads();
        if (tid < BNODES) scn[tid] += t;
        __syncthreads();
    }
    if (tid < BNODES) { noff[tid] = scn[tid] - v; cur[tid] = scn[tid] - v; }
    if (tid == 0) noff[BNODES] = cntb;
    __syncthreads();

    if (!big) {
        if (i0 < cntb) { int q = atomicAdd(&cur[(p0 >> 17) & (BNODES - 1)], 1); lsrc[q] = p0 & 0x1FFFF; }
        if (i1 < cntb) { int q = atomicAdd(&cur[(p1 >> 17) & (BNODES - 1)], 1); lsrc[q] = p1 & 0x1FFFF; }
        if (i2 < cntb) { int q = atomicAdd(&cur[(p2 >> 17) & (BNODES - 1)], 1); lsrc[q] = p2 & 0x1FFFF; }
        if (i3 < cntb) { int q = atomicAdd(&cur[(p3 >> 17) & (BNODES - 1)], 1); lsrc[q] = p3 & 0x1FFFF; }
    } else {
        for (int i = tid; i < cntb; i += 1024) {
            unsigned p = sorted[start + i];
            int q = atomicAdd(&cur[(p >> 17) & (BNODES - 1)], 1);
            sorted2[start + q] = p & 0x1FFFF;
        }
    }
    __syncthreads();

    int g = tid >> 3, gl = tid & 7;
    for (int n = g; n < BNODES; n += 128) {
        int node = (b << BSHIFT) + n;
        if (node >= N_NODES) break;
        int off = noff[n], endn = noff[n + 1];
        int deg = endn - off;
        float4 accA = make_float4(0.f, 0.f, 0.f, 0.f);
        float4 accB = make_float4(0.f, 0.f, 0.f, 0.f);
        int e = off;
        if (!big) {
            for (; e + 4 <= endn; e += 4) {
                int s0 = lsrc[e], s1 = lsrc[e + 1], s2 = lsrc[e + 2], s3 = lsrc[e + 3];
                half8 v0 = *reinterpret_cast<const half8*>(&feat16[(size_t)s0 * D + gl * 8]);
                half8 v1 = *reinterpret_cast<const half8*>(&feat16[(size_t)s1 * D + gl * 8]);
                half8 v2 = *reinterpret_cast<const half8*>(&feat16[(size_t)s2 * D + gl * 8]);
                half8 v3 = *reinterpret_cast<const half8*>(&feat16[(size_t)s3 * D + gl * 8]);
                accA.x += (float)v0[0] + (float)v1[0] + (float)v2[0] + (float)v3[0];
                accA.y += (float)v0[1] + (float)v1[1] + (float)v2[1] + (float)v3[1];
                accA.z += (float)v0[2] + (float)v1[2] + (float)v2[2] + (float)v3[2];
                accA.w += (float)v0[3] + (float)v1[3] + (float)v2[3] + (float)v3[3];
                accB.x += (float)v0[4] + (float)v1[4] + (float)v2[4] + (float)v3[4];
                accB.y += (float)v0[5] + (float)v1[5] + (float)v2[5] + (float)v3[5];
                accB.z += (float)v0[6] + (float)v1[6] + (float)v2[6] + (float)v3[6];
                accB.w += (float)v0[7] + (float)v1[7] + (float)v2[7] + (float)v3[7];
            }
            for (; e < endn; e++) {
                int s = lsrc[e];
                half8 vv = *reinterpret_cast<const half8*>(&feat16[(size_t)s * D + gl * 8]);
                accA.x += (float)vv[0]; accA.y += (float)vv[1];
                accA.z += (float)vv[2]; accA.w += (float)vv[3];
                accB.x += (float)vv[4]; accB.y += (float)vv[5];
                accB.z += (float)vv[6]; accB.w += (float)vv[7];
            }
        } else {
            for (; e < endn; e++) {
                int s = (int)sorted2[start + e];
                half8 vv = *reinterpret_cast<const half8*>(&feat16[(size_t)s * D + gl * 8]);
                accA.x += (float)vv[0]; accA.y += (float)vv[1];
                accA.z += (float)vv[2]; accA.w += (float)vv[3];
                accB.x += (float)vv[4]; accB.y += (float)vv[5];
                accB.z += (float)vv[6]; accB.w += (float)vv[7];
            }
        }
        float inv = (deg > 0) ? 1.0f / (float)deg : 0.0f;
        float4 oA = make_float4(accA.x * inv, accA.y * inv, accA.z * inv, accA.w * inv);
        float4 oB = make_float4(accB.x * inv, accB.y * inv, accB.z * inv, accB.w * inv);
        float* orow = &out[(size_t)node * D + gl * 8];
        *reinterpret_cast<float4*>(orow) = oA;
        *reinterpret_cast<float4*>(orow + 4) = oB;
    }
}

// ---------- fallback (atomic scatter) if ws too small ----------
__global__ void gcn_scatter(const float* __restrict__ feat, const int* __restrict__ src,
                            const int* __restrict__ dst, float* __restrict__ out,
                            float* __restrict__ deg, int n_edges) {
    long long gtid = (long long)blockIdx.x * blockDim.x + threadIdx.x;
    int edge = (int)(gtid >> 6);
    int lane = threadIdx.x & 63;
    if (edge >= n_edges) return;
    atomicAdd(&out[(long long)dst[edge] * D + lane],
              feat[(long long)src[edge] * D + lane]);
    if (lane == 0) atomicAdd(&deg[dst[edge]], 1.0f);
}
__global__ void gcn_finalize(float* __restrict__ out, const float* __restrict__ deg,
                             int total) {
    int i = blockIdx.x * blockDim.x + threadIdx.x;
    if (i >= total) return;
    float dg = deg[i >> 6];
    out[i] = (dg > 0.0f) ? out[i] / dg : 0.0f;
}

extern "C" void kernel_launch(void* const* d_in, const int* in_sizes, int n_in,
                              void* d_out, int out_size, void* d_ws, size_t ws_size,
                              hipStream_t stream) {
    const float* feat = (const float*)d_in[0];
    const int* src = (const int*)d_in[1];
    const int* dst = (const int*)d_in[2];
    float* out = (float*)d_out;
    int n_edges = in_sizes[1];

    int nchunk = (n_edges + CHUNK - 1) / CHUNK;
    size_t ncounts = (size_t)NB * nchunk;
    size_t f16_bytes = (size_t)N_NODES * D * sizeof(_Float16);   // 12.8 MB
    size_t need = f16_bytes + (ncounts + NB + NB + 1) * sizeof(int)
                + (size_t)n_edges * 2 * sizeof(unsigned);

    if (ws_size < need) {
        float* deg = (float*)d_ws;
        int total = N_NODES * D;
        hipMemsetAsync(out, 0, (size_t)total * sizeof(float), stream);
        hipMemsetAsync(deg, 0, (size_t)N_NODES * sizeof(float), stream);
        long long threads = (long long)n_edges * 64;
        int grid = (int)((threads + 255) / 256);
        gcn_scatter<<<grid, 256, 0, stream>>>(feat, src, dst, out, deg, n_edges);
        gcn_finalize<<<(total + 255) / 256, 256, 0, stream>>>(out, deg, total);
        return;
    }

    char* wp = (char*)d_ws;
    _Float16* feat16 = (_Float16*)wp;            wp += f16_bytes;
    int* counts = (int*)wp;                      wp += ncounts * sizeof(int);
    int* totals = (int*)wp;                      wp += (size_t)NB * sizeof(int);
    int* base = (int*)wp;                        wp += (size_t)(NB + 1) * sizeof(int);
    unsigned* sorted = (unsigned*)wp;            wp += (size_t)n_edges * sizeof(unsigned);
    unsigned* sorted2 = (unsigned*)wp;           // spill path only

    int n4pairs = N_NODES * D / 8;
    int chgrid = nchunk + 256;                   // hist blocks + 256 dedicated conv blocks
    convhist<<<chgrid, 1024, 0, stream>>>((const float4*)feat, (float4*)feat16,
                                          n4pairs, dst, counts, nchunk, n_edges);
    scanB<<<NB, 256, 0, stream>>>(counts, totals, nchunk);
    baseK<<<1, 1024, 0, stream>>>(totals, base, n_edges);
    scatter2<<<nchunk, 1024, 0, stream>>>(src, dst, counts, base, sorted,
                                          nchunk, n_edges);
    sortGather<<<NB, 1024, 0, stream>>>(feat16, sorted, base, sorted2, out);
}